// Round 3
// baseline (72.655 us; speedup 1.0000x reference)
//
#include <hip/hip_runtime.h>

#define F 32
#define D_HALF 256
#define NP 22
#define BLOCKS 1024
#define TPB 256

// kTable[p-1] = sign_p / (p! * 32); sin terms p odd, cos terms p even.
__device__ constexpr float kTable[NP] = {
     3.125e-2f,                // p=1
    -1.5625e-2f,               // p=2
    -5.2083333333333336e-3f,   // p=3
     1.3020833333333333e-3f,   // p=4
     2.6041666666666666e-4f,   // p=5
    -4.3402777777777778e-5f,   // p=6
    -6.2003968253968254e-6f,   // p=7
     7.7504960317460317e-7f,   // p=8
     8.6116622574955908e-8f,   // p=9
    -8.6116622574955908e-9f,   // p=10
    -7.8287838704505371e-10f,  // p=11
     6.5239865587087809e-11f,  // p=12
     5.0184511989929083e-12f,  // p=13
    -3.5846079992806488e-13f,  // p=14
    -2.3897386661870992e-14f,  // p=15
     1.4935866663669370e-15f,  // p=16
     8.7858039198055118e-17f,  // p=17
    -4.8810021776697288e-18f,  // p=18
    -2.5689485145630152e-19f,  // p=19
     1.2844742572815076e-20f,  // p=20
     6.1165440822928934e-22f,  // p=21
    -2.7802473101331334e-23f   // p=22
};

__global__ __launch_bounds__(TPB) void pe_kernel(const float* __restrict__ x,
                                                 float2* __restrict__ out,
                                                 int B) {
    const int lane = threadIdx.x & 63;
    const int fl   = lane & 31;   // sample index within the row
    const int half = lane >> 5;   // 0 -> row 2rp, 1 -> row 2rp+1
    const int gwave  = blockIdx.x * (TPB / 64) + (threadIdx.x >> 6);
    const int nwaves = gridDim.x * (TPB / 64);
    const int npairs = B >> 1;

    const float kExp = -0.05190512648261503f;  // -log2(10000)/256

    for (int rp = gwave; rp < npairs; rp += nwaves) {
        const int r = (rp << 1) + half;
        // Whole wave reads 256 contiguous bytes (two 32-float rows).
        const float v = x[r * F + fl];

        // Powers v^1..v^22, then butterfly-reduce within each 32-lane half.
        // Masks 1..16 never cross the 32-lane boundary, so each half reduces
        // its own row; afterwards EVERY lane holds its row's 22 moments.
        float mom[NP];
        float p = v;
#pragma unroll
        for (int k = 0; k < NP; ++k) { mom[k] = p; p *= v; }
#pragma unroll
        for (int k = 0; k < NP; ++k) {
            float s = mom[k];
            s += __shfl_xor(s, 1);
            s += __shfl_xor(s, 2);
            s += __shfl_xor(s, 4);
            s += __shfl_xor(s, 8);
            s += __shfl_xor(s, 16);
            mom[k] = s * kTable[k];  // sign/(p!*32) folded in
        }

        // Each lane evaluates 8 (sin,cos) output pairs for its row.
        float2* orow = out + r * D_HALF;
#pragma unroll
        for (int m = 0; m < 8; ++m) {
            const int j = fl + 32 * m;
            const float d = __builtin_amdgcn_exp2f((float)j * kExp);
            const float t = d * d;

            float s = mom[20];
            s = fmaf(s, t, mom[18]);
            s = fmaf(s, t, mom[16]);
            s = fmaf(s, t, mom[14]);
            s = fmaf(s, t, mom[12]);
            s = fmaf(s, t, mom[10]);
            s = fmaf(s, t, mom[8]);
            s = fmaf(s, t, mom[6]);
            s = fmaf(s, t, mom[4]);
            s = fmaf(s, t, mom[2]);
            s = fmaf(s, t, mom[0]);

            float c = mom[21];
            c = fmaf(c, t, mom[19]);
            c = fmaf(c, t, mom[17]);
            c = fmaf(c, t, mom[15]);
            c = fmaf(c, t, mom[13]);
            c = fmaf(c, t, mom[11]);
            c = fmaf(c, t, mom[9]);
            c = fmaf(c, t, mom[7]);
            c = fmaf(c, t, mom[5]);
            c = fmaf(c, t, mom[3]);
            c = fmaf(c, t, mom[1]);
            c = fmaf(c, t, 1.0f);

            orow[j] = make_float2(s * d, c);
        }
    }
}

extern "C" void kernel_launch(void* const* d_in, const int* in_sizes, int n_in,
                              void* d_out, int out_size, void* d_ws, size_t ws_size,
                              hipStream_t stream) {
    const float* x = (const float*)d_in[0];
    float2* out = (float2*)d_out;
    const int B = in_sizes[0] / F;  // 16384
    pe_kernel<<<BLOCKS, TPB, 0, stream>>>(x, out, B);
}

// Round 4
// 68.436 us; speedup vs baseline: 1.0616x; 1.0616x over previous
//
#include <hip/hip_runtime.h>

#define F 32
#define D_HALF 256
#define NP 14        // Taylor powers x^1..x^14; remainder <= theta^15/15!/32 ~ 5e-4 at |x|max~4.9
#define TPB 256
#define BLOCKS 2048  // 2048*4 waves == 8192 row-pairs -> exactly one pair per wave

// kTable[p-1] = sign_p / (p! * 32); sin terms p odd, cos terms p even.
__device__ constexpr float kTable[NP] = {
     3.125e-2f,               // p=1
    -1.5625e-2f,              // p=2
    -5.2083333333333e-3f,     // p=3
     1.3020833333333e-3f,     // p=4
     2.6041666666667e-4f,     // p=5
    -4.3402777777778e-5f,     // p=6
    -6.2003968253968e-6f,     // p=7
     7.7504960317460e-7f,     // p=8
     8.6116622574956e-8f,     // p=9
    -8.6116622574956e-9f,     // p=10
    -7.8287838704505e-10f,    // p=11
     6.5239865587088e-11f,    // p=12
     5.0184511989929e-12f,    // p=13
    -3.5846079992806e-13f     // p=14
};

__global__ __launch_bounds__(TPB) void pe_kernel(const float* __restrict__ x,
                                                 float4* __restrict__ out,
                                                 int B) {
    const int lane = threadIdx.x & 63;
    const int fl   = lane & 31;   // sample index within the row / pair-group index
    const int half = lane >> 5;   // 0 -> row 2rp, 1 -> row 2rp+1
    const int gwave  = blockIdx.x * (TPB / 64) + (threadIdx.x >> 6);
    const int nwaves = gridDim.x * (TPB / 64);
    const int npairs = B >> 1;

    const float kExp = -0.05190512648261503f;  // -log2(10000)/256

    // Hoisted: each lane owns output pairs j0=2*fl+64m and j1=j0+1 (m=0..3).
    float d0[4], t0[4], d1[4], t1[4];
#pragma unroll
    for (int m = 0; m < 4; ++m) {
        const int j0 = 2 * fl + 64 * m;
        d0[m] = __builtin_amdgcn_exp2f((float)j0 * kExp);
        d1[m] = __builtin_amdgcn_exp2f((float)(j0 + 1) * kExp);
        t0[m] = d0[m] * d0[m];
        t1[m] = d1[m] * d1[m];
    }

    for (int rp = gwave; rp < npairs; rp += nwaves) {
        const int r = (rp << 1) + half;
        // Whole wave reads 256 contiguous bytes (two 32-float rows).
        const float v = x[r * F + fl];

        // Powers v^1..v^14, butterfly-reduce within each 32-lane half;
        // afterwards every lane holds its row's 14 scaled moments.
        float mom[NP];
        float p = v;
#pragma unroll
        for (int k = 0; k < NP; ++k) { mom[k] = p; p *= v; }
#pragma unroll
        for (int k = 0; k < NP; ++k) {
            float s = mom[k];
            s += __shfl_xor(s, 1);
            s += __shfl_xor(s, 2);
            s += __shfl_xor(s, 4);
            s += __shfl_xor(s, 8);
            s += __shfl_xor(s, 16);
            mom[k] = s * kTable[k];  // sign/(p!*32) folded in
        }

        // Each lane stores 4 float4s = 8 (sin,cos) pairs, coalesced.
        float4* orow = out + r * (D_HALF / 2);
#pragma unroll
        for (int m = 0; m < 4; ++m) {
            // pair j0 = 2*fl + 64m
            float s0 = mom[12];
            s0 = fmaf(s0, t0[m], mom[10]);
            s0 = fmaf(s0, t0[m], mom[8]);
            s0 = fmaf(s0, t0[m], mom[6]);
            s0 = fmaf(s0, t0[m], mom[4]);
            s0 = fmaf(s0, t0[m], mom[2]);
            s0 = fmaf(s0, t0[m], mom[0]);
            float c0 = mom[13];
            c0 = fmaf(c0, t0[m], mom[11]);
            c0 = fmaf(c0, t0[m], mom[9]);
            c0 = fmaf(c0, t0[m], mom[7]);
            c0 = fmaf(c0, t0[m], mom[5]);
            c0 = fmaf(c0, t0[m], mom[3]);
            c0 = fmaf(c0, t0[m], mom[1]);
            c0 = fmaf(c0, t0[m], 1.0f);

            // pair j1 = j0 + 1
            float s1 = mom[12];
            s1 = fmaf(s1, t1[m], mom[10]);
            s1 = fmaf(s1, t1[m], mom[8]);
            s1 = fmaf(s1, t1[m], mom[6]);
            s1 = fmaf(s1, t1[m], mom[4]);
            s1 = fmaf(s1, t1[m], mom[2]);
            s1 = fmaf(s1, t1[m], mom[0]);
            float c1 = mom[13];
            c1 = fmaf(c1, t1[m], mom[11]);
            c1 = fmaf(c1, t1[m], mom[9]);
            c1 = fmaf(c1, t1[m], mom[7]);
            c1 = fmaf(c1, t1[m], mom[5]);
            c1 = fmaf(c1, t1[m], mom[3]);
            c1 = fmaf(c1, t1[m], mom[1]);
            c1 = fmaf(c1, t1[m], 1.0f);

            orow[fl + 32 * m] = make_float4(s0 * d0[m], c0, s1 * d1[m], c1);
        }
    }
}

extern "C" void kernel_launch(void* const* d_in, const int* in_sizes, int n_in,
                              void* d_out, int out_size, void* d_ws, size_t ws_size,
                              hipStream_t stream) {
    const float* x = (const float*)d_in[0];
    float4* out = (float4*)d_out;
    const int B = in_sizes[0] / F;  // 16384
    pe_kernel<<<BLOCKS, TPB, 0, stream>>>(x, out, B);
}